// Round 9
// baseline (830.396 us; speedup 1.0000x reference)
//
#include <hip/hip_runtime.h>

// ---------------------------------------------------------------------------
// GCN 3-layer forward on MI355X — radix CSR build + bf16 MFMA GEMMs with
// dinv folded into the GEMM epilogue (hA = dinv * (xW)), so aggregation is
// out[d] = dinv[d] * (sum_e ew*hA[src] + hA[d])  — norm pass ELIMINATED.
// R17 = R15 third attempt (R15/R16 were infra failures: container died in
// acquisition both times; diff audited twice — no reachable OOB/hang; error
// signature is bursty broker outage, not a kernel verdict). Theory under
// test: build de-machinery'd — within-bucket edge order was never
// deterministic (LDS cursor order is schedule-dependent) so the
// histG/block_offs apparatus existed for nothing: passA now only produces
// bucket totals (LDS hist -> one global atomic per bucket per block); passB
// claims slots via global per-bucket atomic cursors (contended-same-address
// atomics pipeline in L2, unlike R4/R5's scattered-sector atomics).
// histG + blockOffs deleted. 13 -> 12 dispatches.
// PRE-COMMIT: fails again -> resubmit R14 verbatim to disambiguate infra.
// R14 LESSON: launch gaps ~1us in a captured graph — launch-count alone is
// not a lever.
// R12: agg = 16 nodes/block-of-256, block edge segment staged in LDS, slot
// chains deep-unrolled (agg64 x8, agg32 x4), predicated tail to row 0.
// R13 LESSON: single-block fused reduce re-created R9 latency-starvation.
// R11 LESSON: in-flight = unroll x resident waves. R9 LESSON: edge-centric
// LDS-atomic agg 9x worse. R8: agg FETCH insensitive to edge payload bytes.
// ---------------------------------------------------------------------------

typedef unsigned int uint32;
typedef __attribute__((ext_vector_type(8))) short bf16x8;
typedef __attribute__((ext_vector_type(4))) float f32x4;

#define G 256          // blocks in pass A / pass B
#define MAXB 512       // max coarse buckets (256-node buckets, N <= 131072)
#define ECAP 1024      // staged edges per agg block (8 KB LDS)

__device__ __forceinline__ ushort f2bf(float v) {
    uint32 u = __float_as_uint(v);
    u += 0x7fff + ((u >> 16) & 1);  // round to nearest even
    return (ushort)(u >> 16);
}
__device__ __forceinline__ uint32 pack2bf(float a, float b) {
    return (uint32)f2bf(a) | ((uint32)f2bf(b) << 16);
}
__device__ __forceinline__ float bf_lo(uint32 u) {
    return __uint_as_float(u << 16);
}
__device__ __forceinline__ float bf_hi(uint32 u) {
    return __uint_as_float(u & 0xffff0000u);
}

// ---- pass A: per-block LDS histogram -> global-atomic bucket totals,
// + W transposes folded onto the first 14 blocks ----
__global__ __launch_bounds__(1024) void passA_count_kernel(
    const int* __restrict__ dst, int* __restrict__ totals,
    const float* __restrict__ W1, const float* __restrict__ W2,
    const float* __restrict__ W3, ushort* __restrict__ W1T,
    ushort* __restrict__ W2T, ushort* __restrict__ W3T, int E, int EPB) {
    __shared__ int h[MAXB];
    const int tid = threadIdx.x, g = blockIdx.x;
    // ---- folded W transposes: 14336 elems on blocks 0..13 ----
    int gi = g * 1024 + tid;
    if (gi < 8192) {                      // W1: 128x64
        int k = gi / 64, m = gi % 64;
        W1T[m * 128 + k] = f2bf(W1[gi]);
    } else if (gi < 12288) {              // W2: 64x64
        int j = gi - 8192, k = j / 64, m = j % 64;
        W2T[m * 64 + k] = f2bf(W2[j]);
    } else if (gi < 14336) {              // W3: 64x32
        int j = gi - 12288, k = j / 32, m = j % 32;
        W3T[m * 64 + k] = f2bf(W3[j]);
    }
    if (tid < MAXB) h[tid] = 0;
    __syncthreads();
    const int e0 = g * EPB, e1 = min(e0 + EPB, E);
    for (int e = e0 + tid; e < e1; e += 1024) atomicAdd(&h[dst[e] >> 8], 1);
    __syncthreads();
    if (tid < MAXB && h[tid] > 0) atomicAdd(&totals[tid], h[tid]);
}

// ---- exclusive scan over bucket totals -> bucketBase[NB+1] + seed the
// global passB cursors (1 block) ----
__global__ __launch_bounds__(512) void bucket_scan_kernel(
    const int* __restrict__ totals, int* __restrict__ bucketBase,
    int* __restrict__ bucketCur, int NB, int E) {
    __shared__ int s[512];
    const int t = threadIdx.x;
    int v = (t < NB) ? totals[t] : 0;
    s[t] = v;
    __syncthreads();
    for (int off = 1; off < 512; off <<= 1) {
        int u = (t >= off) ? s[t - off] : 0;
        __syncthreads();
        s[t] += u;
        __syncthreads();
    }
    if (t < NB) {
        bucketBase[t] = s[t] - v;  // exclusive
        bucketCur[t] = s[t] - v;   // passB write cursor
    }
    if (t == 0) bucketBase[NB] = E;
}

// ---- pass B: scatter edges to their coarse-bucket segment via global
// per-bucket atomic cursors (within-bucket order nondeterministic — fine,
// fine_kernel re-sorts by local dst and fp32 sum order was never fixed) ----
__global__ __launch_bounds__(1024) void passB_scatter_kernel(
    const int* __restrict__ src, const int* __restrict__ dst,
    const float* __restrict__ ew, int* __restrict__ bucketCur,
    int2* __restrict__ tmp, int E, int EPB) {
    const int tid = threadIdx.x, g = blockIdx.x;
    const int e0 = g * EPB, e1 = min(e0 + EPB, E);
    for (int e = e0 + tid; e < e1; e += 1024) {
        int d = dst[e];
        int pos = atomicAdd(&bucketCur[d >> 8], 1);  // global cursor
        // pack: src (17 bits) | local-dst (8 bits) << 17 ; .y = ew bits
        tmp[pos] = make_int2(src[e] | ((d & 255) << 17),
                             __float_as_int(ew[e]));
    }
}

// ---- fine: per-bucket LDS counting sort -> edges(src|ldst,ew) + offs + dinv
__global__ __launch_bounds__(512) void fine_kernel(
    const int2* __restrict__ tmp, const int* __restrict__ bucketBase,
    int* __restrict__ offs, int2* __restrict__ edges,
    float* __restrict__ dinv, int N, int E, int NB) {
    __shared__ int cnt[256];
    __shared__ int pos0[256];
    __shared__ float degf[256];
    const int t = threadIdx.x, b = blockIdx.x;
    const int base = bucketBase[b], endb = bucketBase[b + 1];
    if (t < 256) { cnt[t] = 0; degf[t] = 0.0f; }
    __syncthreads();
    for (int j = base + t; j < endb; j += 512)
        atomicAdd(&cnt[(tmp[j].x >> 17) & 255], 1);
    __syncthreads();
    int v = 0;
    if (t < 256) { v = cnt[t]; pos0[t] = v; }
    __syncthreads();
    for (int off = 1; off < 256; off <<= 1) {  // Hillis-Steele
        int u = 0;
        if (t < 256 && t >= off) u = pos0[t - off];
        __syncthreads();
        if (t < 256) pos0[t] += u;
        __syncthreads();
    }
    if (t < 256) { pos0[t] -= v; cnt[t] = 0; }  // exclusive; reset cursors
    __syncthreads();
    const int node = (b << 8) + t;
    if (t < 256 && node < N) offs[node] = base + pos0[t];
    if (b == NB - 1 && t == 0) offs[N] = E;
    for (int j = base + t; j < endb; j += 512) {
        int2 ed = tmp[j];
        int ldst = (ed.x >> 17) & 255;
        int p = base + pos0[ldst] + atomicAdd(&cnt[ldst], 1);
        edges[p] = ed;  // keep packed local-dst bits (harmless; agg masks)
        atomicAdd(&degf[ldst], __int_as_float(ed.y));  // LDS float atomic
    }
    __syncthreads();
    if (t < 256 && node < N) dinv[node] = rsqrtf(1.0f + degf[t]);
}

// ---- MFMA GEMM: out_bf16[n] = dinv[n] * (f(in[n]) @ W).  4 waves x 16-row
// tile, v_mfma_f32_16x16x32_bf16; LDS rows padded +8 bf16. m89 layouts. ----
template <int K, int M, bool RELU, bool BIAS, bool INBF16>
__global__ __launch_bounds__(256) void gemm_mfma_kernel(
    const void* __restrict__ in_, const ushort* __restrict__ WT,
    const float* __restrict__ bias_in, const float* __restrict__ dinv,
    ushort* __restrict__ out, int N) {
    constexpr int KP = K + 8;    // padded LDS row stride (bf16 units)
    constexpr int CCH = M / 16;  // col chunks
    __shared__ __align__(16) ushort Xl[64 * KP];
    __shared__ __align__(16) ushort Wl[M * KP];
    const int tid = threadIdx.x;
    const int node0 = blockIdx.x * 64;

    for (int i = tid; i < M * (K / 8); i += 256) {
        int row = i / (K / 8), kc = i % (K / 8);
        uint4 u = ((const uint4*)WT)[i];
        *(uint4*)&Wl[row * KP + kc * 8] = u;
    }
    if (INBF16) {
        for (int i = tid; i < 64 * (K / 8); i += 256) {
            int row = i / (K / 8), kc = i % (K / 8);
            int node = node0 + row;
            uint4 u = make_uint4(0, 0, 0, 0);
            if (node < N) {
                u = ((const uint4*)in_)[(size_t)node * (K / 8) + kc];
                if (BIAS || RELU) {
                    float v[8];
                    v[0] = bf_lo(u.x); v[1] = bf_hi(u.x);
                    v[2] = bf_lo(u.y); v[3] = bf_hi(u.y);
                    v[4] = bf_lo(u.z); v[5] = bf_hi(u.z);
                    v[6] = bf_lo(u.w); v[7] = bf_hi(u.w);
#pragma unroll
                    for (int j = 0; j < 8; ++j) {
                        if (BIAS) v[j] += bias_in[kc * 8 + j];
                        if (RELU) v[j] = fmaxf(v[j], 0.f);
                    }
                    u.x = pack2bf(v[0], v[1]); u.y = pack2bf(v[2], v[3]);
                    u.z = pack2bf(v[4], v[5]); u.w = pack2bf(v[6], v[7]);
                }
            }
            *(uint4*)&Xl[row * KP + kc * 8] = u;
        }
    } else {
        for (int i = tid; i < 64 * (K / 4); i += 256) {
            int row = i / (K / 4), kc = i % (K / 4);
            int node = node0 + row;
            uint2 p = make_uint2(0, 0);
            if (node < N) {
                float4 v = ((const float4*)in_)[(size_t)node * (K / 4) + kc];
                p.x = pack2bf(v.x, v.y);
                p.y = pack2bf(v.z, v.w);
            }
            *(uint2*)&Xl[row * KP + kc * 4] = p;
        }
    }
    __syncthreads();

    const int wv = tid >> 6, lane = tid & 63;
    const int r16 = lane & 15, quad = lane >> 4;
    f32x4 acc[CCH];
#pragma unroll
    for (int c = 0; c < CCH; ++c) acc[c] = (f32x4){0.f, 0.f, 0.f, 0.f};
#pragma unroll
    for (int kq = 0; kq < K / 32; ++kq) {
        bf16x8 a = *(const bf16x8*)
            &Xl[(wv * 16 + r16) * KP + kq * 32 + quad * 8];
#pragma unroll
        for (int c = 0; c < CCH; ++c) {
            bf16x8 b = *(const bf16x8*)
                &Wl[(c * 16 + r16) * KP + kq * 32 + quad * 8];
            acc[c] = __builtin_amdgcn_mfma_f32_16x16x32_bf16(a, b, acc[c],
                                                             0, 0, 0);
        }
    }
    // D: col = lane&15, row = quad*4 + reg; scale row by dinv[node]
#pragma unroll
    for (int r = 0; r < 4; ++r) {
        int node = node0 + wv * 16 + quad * 4 + r;
        float dv = (node < N) ? dinv[node] : 0.f;
#pragma unroll
        for (int c = 0; c < CCH; ++c) {
            if (node < N)
                out[(size_t)node * M + c * 16 + r16] = f2bf(acc[c][r] * dv);
        }
    }
}

// ---- CSR aggregate, 64-wide bf16 rows (128 B). 16 nodes/block, 16-lane
// node group (8 r-lanes x 2 slots). Block edge segment staged in LDS; slot
// chain unrolled x8 -> degree-16 node done in ONE iteration, 8 gathers in
// flight. Predicated tail -> row 0 (L1-hot), weight 0. out = dinv*(acc+self).
__global__ __launch_bounds__(256) void agg64_kernel(
    const ushort* __restrict__ h, const int2* __restrict__ edges,
    const int* __restrict__ offs, const float* __restrict__ dinv,
    ushort* __restrict__ out, int N) {
    __shared__ int soffs[17];
    __shared__ float sdinv[16];
    __shared__ int2 eLds[ECAP];
    const int tid = threadIdx.x;
    const int n0 = blockIdx.x * 16;
    if (tid < 17) soffs[tid] = offs[min(n0 + tid, N)];
    if (tid < 16) sdinv[tid] = (n0 + tid < N) ? dinv[n0 + tid] : 0.0f;
    __syncthreads();
    const int eBase = soffs[0];
    const int eTot = soffs[16] - eBase;
    for (int i = tid; i < min(eTot, ECAP); i += 256)
        eLds[i] = edges[eBase + i];

    const int lane = tid & 63, wv = tid >> 6;
    const int r = lane & 7;           // uint4 index within the 128 B row
    const int slot = (lane >> 3) & 1; // 2 edge slots per node
    const int li = wv * 4 + (lane >> 4);  // local node 0..15
    const int node = n0 + li;
    const uint4* __restrict__ h4 = (const uint4*)h;

    // self row issued before the staging barrier — overlaps it
    uint4 hv = make_uint4(0u, 0u, 0u, 0u);
    if (slot == 0 && node < N) hv = h4[(size_t)node * 8 + r];
    __syncthreads();

    const int start = soffs[li], end = soffs[li + 1];
    float acc[8] = {};
    if (eTot <= ECAP) {  // fast path: edges from LDS
        for (int j = start + slot; j < end; j += 16) {
            int2 e[8];
            uint4 u[8];
#pragma unroll
            for (int k = 0; k < 8; ++k) {
                int idx = j + 2 * k;
                e[k] = (idx < end) ? eLds[idx - eBase] : make_int2(0, 0);
            }
#pragma unroll
            for (int k = 0; k < 8; ++k)
                u[k] = h4[(size_t)(e[k].x & 0x1FFFF) * 8 + r];
#pragma unroll
            for (int k = 0; k < 8; ++k) {
                float w = __int_as_float(e[k].y);
                acc[0] += bf_lo(u[k].x) * w; acc[1] += bf_hi(u[k].x) * w;
                acc[2] += bf_lo(u[k].y) * w; acc[3] += bf_hi(u[k].y) * w;
                acc[4] += bf_lo(u[k].z) * w; acc[5] += bf_hi(u[k].z) * w;
                acc[6] += bf_lo(u[k].w) * w; acc[7] += bf_hi(u[k].w) * w;
            }
        }
    } else {  // overflow fallback: edges straight from global (block-uniform)
        for (int j = start + slot; j < end; j += 16) {
            int2 e[8];
            uint4 u[8];
#pragma unroll
            for (int k = 0; k < 8; ++k) {
                int idx = j + 2 * k;
                e[k] = (idx < end) ? edges[idx] : make_int2(0, 0);
            }
#pragma unroll
            for (int k = 0; k < 8; ++k)
                u[k] = h4[(size_t)(e[k].x & 0x1FFFF) * 8 + r];
#pragma unroll
            for (int k = 0; k < 8; ++k) {
                float w = __int_as_float(e[k].y);
                acc[0] += bf_lo(u[k].x) * w; acc[1] += bf_hi(u[k].x) * w;
                acc[2] += bf_lo(u[k].y) * w; acc[3] += bf_hi(u[k].y) * w;
                acc[4] += bf_lo(u[k].z) * w; acc[5] += bf_hi(u[k].z) * w;
                acc[6] += bf_lo(u[k].w) * w; acc[7] += bf_hi(u[k].w) * w;
            }
        }
    }
#pragma unroll
    for (int k = 0; k < 8; ++k) acc[k] += __shfl_xor(acc[k], 8);
    if (slot == 0 && node < N) {
        float sc = sdinv[li];
        uint4 o;
        o.x = pack2bf((acc[0] + bf_lo(hv.x)) * sc, (acc[1] + bf_hi(hv.x)) * sc);
        o.y = pack2bf((acc[2] + bf_lo(hv.y)) * sc, (acc[3] + bf_hi(hv.y)) * sc);
        o.z = pack2bf((acc[4] + bf_lo(hv.z)) * sc, (acc[5] + bf_hi(hv.z)) * sc);
        o.w = pack2bf((acc[6] + bf_lo(hv.w)) * sc, (acc[7] + bf_hi(hv.w)) * sc);
        ((uint4*)out)[(size_t)node * 8 + r] = o;
    }
}

// ---- CSR aggregate, 32-wide bf16 rows (64 B), final layer. 16 nodes/block,
// 16-lane node group (4 r-lanes x 4 slots). LDS-staged edges; chain unrolled
// x4 -> degree-16 node in one iteration, 4 gathers in flight.
// out = dinv*(acc+self) + b3, fp32; block mean -> spread buckets. ----
__global__ __launch_bounds__(256) void agg32_final_kernel(
    const ushort* __restrict__ h, const int2* __restrict__ edges,
    const int* __restrict__ offs, const float* __restrict__ dinv,
    const float* __restrict__ b3, float* __restrict__ out,
    float* __restrict__ mean_acc, int N) {
    __shared__ int soffs[17];
    __shared__ float sdinv[16];
    __shared__ float ssum[32];
    __shared__ int2 eLds[ECAP];
    const int tid = threadIdx.x;
    const int n0 = blockIdx.x * 16;
    if (tid < 17) soffs[tid] = offs[min(n0 + tid, N)];
    if (tid < 16) sdinv[tid] = (n0 + tid < N) ? dinv[n0 + tid] : 0.0f;
    if (tid < 32) ssum[tid] = 0.0f;
    __syncthreads();
    const int eBase = soffs[0];
    const int eTot = soffs[16] - eBase;
    for (int i = tid; i < min(eTot, ECAP); i += 256)
        eLds[i] = edges[eBase + i];

    const int lane = tid & 63, wv = tid >> 6;
    const int r = lane & 3;           // uint4 index within the 64 B row
    const int slot = (lane >> 2) & 3; // 4 edge slots per node
    const int li = wv * 4 + (lane >> 4);  // local node 0..15
    const int node = n0 + li;
    const uint4* __restrict__ h4 = (const uint4*)h;

    uint4 hv = make_uint4(0u, 0u, 0u, 0u);
    if (slot == 0 && node < N) hv = h4[(size_t)node * 4 + r];
    __syncthreads();

    const int start = soffs[li], end = soffs[li + 1];
    float acc[8] = {};
    if (eTot <= ECAP) {  // fast path: edges from LDS
        for (int j = start + slot; j < end; j += 16) {
            int2 e[4];
            uint4 u[4];
#pragma unroll
            for (int k = 0; k < 4; ++k) {
                int idx = j + 4 * k;
                e[k] = (idx < end) ? eLds[idx - eBase] : make_int2(0, 0);
            }
#pragma unroll
            for (int k = 0; k < 4; ++k)
                u[k] = h4[(size_t)(e[k].x & 0x1FFFF) * 4 + r];
#pragma unroll
            for (int k = 0; k < 4; ++k) {
                float w = __int_as_float(e[k].y);
                acc[0] += bf_lo(u[k].x) * w; acc[1] += bf_hi(u[k].x) * w;
                acc[2] += bf_lo(u[k].y) * w; acc[3] += bf_hi(u[k].y) * w;
                acc[4] += bf_lo(u[k].z) * w; acc[5] += bf_hi(u[k].z) * w;
                acc[6] += bf_lo(u[k].w) * w; acc[7] += bf_hi(u[k].w) * w;
            }
        }
    } else {  // overflow fallback (block-uniform)
        for (int j = start + slot; j < end; j += 16) {
            int2 e[4];
            uint4 u[4];
#pragma unroll
            for (int k = 0; k < 4; ++k) {
                int idx = j + 4 * k;
                e[k] = (idx < end) ? edges[idx] : make_int2(0, 0);
            }
#pragma unroll
            for (int k = 0; k < 4; ++k)
                u[k] = h4[(size_t)(e[k].x & 0x1FFFF) * 4 + r];
#pragma unroll
            for (int k = 0; k < 4; ++k) {
                float w = __int_as_float(e[k].y);
                acc[0] += bf_lo(u[k].x) * w; acc[1] += bf_hi(u[k].x) * w;
                acc[2] += bf_lo(u[k].y) * w; acc[3] += bf_hi(u[k].y) * w;
                acc[4] += bf_lo(u[k].z) * w; acc[5] += bf_hi(u[k].z) * w;
                acc[6] += bf_lo(u[k].w) * w; acc[7] += bf_hi(u[k].w) * w;
            }
        }
    }
#pragma unroll
    for (int k = 0; k < 8; ++k) {
        acc[k] += __shfl_xor(acc[k], 4);
        acc[k] += __shfl_xor(acc[k], 8);
    }
    if (slot == 0 && node < N) {
        float sc = sdinv[li];
        const float4* b34 = (const float4*)b3;
        float4 bA = b34[r * 2], bB = b34[r * 2 + 1];
        float4 o0, o1;
        o0.x = (acc[0] + bf_lo(hv.x)) * sc + bA.x;
        o0.y = (acc[1] + bf_hi(hv.x)) * sc + bA.y;
        o0.z = (acc[2] + bf_lo(hv.y)) * sc + bA.z;
        o0.w = (acc[3] + bf_hi(hv.y)) * sc + bA.w;
        o1.x = (acc[4] + bf_lo(hv.z)) * sc + bB.x;
        o1.y = (acc[5] + bf_hi(hv.z)) * sc + bB.y;
        o1.z = (acc[6] + bf_lo(hv.w)) * sc + bB.z;
        o1.w = (acc[7] + bf_hi(hv.w)) * sc + bB.w;
        ((float4*)out)[(size_t)node * 8 + r * 2] = o0;
        ((float4*)out)[(size_t)node * 8 + r * 2 + 1] = o1;
        int fb = r * 8;
        atomicAdd(&ssum[fb + 0], o0.x); atomicAdd(&ssum[fb + 1], o0.y);
        atomicAdd(&ssum[fb + 2], o0.z); atomicAdd(&ssum[fb + 3], o0.w);
        atomicAdd(&ssum[fb + 4], o1.x); atomicAdd(&ssum[fb + 5], o1.y);
        atomicAdd(&ssum[fb + 6], o1.z); atomicAdd(&ssum[fb + 7], o1.w);
    }
    __syncthreads();
    if (tid < 32) {
        int bucket = blockIdx.x & 127;  // spread-bucket mean (R2 lesson)
        atomicAdd(&mean_acc[bucket * 32 + tid], ssum[tid]);
    }
}

__global__ void write_mean_kernel(const float* __restrict__ mean_acc,
                                  float* __restrict__ out_tail, float invN) {
    int f = threadIdx.x;
    if (f < 32) {
        float s = 0.0f;
        for (int b = 0; b < 128; ++b) s += mean_acc[b * 32 + f];
        out_tail[f] = s * invN;
    }
}

extern "C" void kernel_launch(void* const* d_in, const int* in_sizes, int n_in,
                              void* d_out, int out_size, void* d_ws,
                              size_t ws_size, hipStream_t stream) {
    const float* x  = (const float*)d_in[0];
    const int*   ei = (const int*)d_in[1];
    const float* ew = (const float*)d_in[2];
    const float* W1 = (const float*)d_in[3];
    const float* b1 = (const float*)d_in[4];
    const float* W2 = (const float*)d_in[5];
    const float* b2 = (const float*)d_in[6];
    const float* W3 = (const float*)d_in[7];
    const float* b3 = (const float*)d_in[8];

    const int N = in_sizes[0] / 128;
    const int E = in_sizes[1] / 2;
    const int* src = ei;
    const int* dst = ei + E;

    const int NB = (N + 255) >> 8;          // 256-node coarse buckets
    const int EPB = (E + G - 1) / G;        // edges per pass-A/B block

    float* out = (float*)d_out;
    char* wsp = (char*)d_ws;
    auto carve = [&](size_t bytes) {
        char* p = wsp;
        wsp += (bytes + 255) & ~(size_t)255;
        return p;
    };
    float*  dinv       = (float*)carve((size_t)N * 4);
    int*    offs       = (int*)carve((size_t)(N + 1) * 4);
    int*    bucketBase = (int*)carve((MAXB + 1) * 4);
    int*    bucketCur  = (int*)carve(MAXB * 4);
    float*  mean       = (float*)carve(128 * 32 * 4);   // 16384 B
    int*    totals     = (int*)carve(MAXB * 4);         // contiguous w/ mean
    int2*   tmp        = (int2*)carve((size_t)E * 8);
    int2*   edges      = (int2*)carve((size_t)E * 8);
    ushort* hA         = (ushort*)carve((size_t)N * 64 * 2);
    ushort* hB         = (ushort*)carve((size_t)N * 64 * 2);
    ushort* W1T        = (ushort*)carve(128 * 64 * 2);
    ushort* W2T        = (ushort*)carve(64 * 64 * 2);
    ushort* W3T        = (ushort*)carve(64 * 32 * 2);

    const int nb_a = (N + 15) / 16;  // agg kernels: 16 nodes per 256-block
    const int nb_g = (N + 63) / 64;  // MFMA gemm: 64 nodes/block

    // one memset covers mean (16384 B) + totals (2048 B), carved contiguous
    hipMemsetAsync(mean, 0, 128 * 32 * 4 + MAXB * 4, stream);

    // ---- CSR build: LDS hist -> totals (+W transposes) -> scan (+cursor
    //      seed) -> global-cursor scatter -> fine counting sort ----
    passA_count_kernel<<<G, 1024, 0, stream>>>(dst, totals, W1, W2, W3,
                                               W1T, W2T, W3T, E, EPB);
    bucket_scan_kernel<<<1, 512, 0, stream>>>(totals, bucketBase, bucketCur,
                                              NB, E);
    passB_scatter_kernel<<<G, 1024, 0, stream>>>(src, dst, ew, bucketCur, tmp,
                                                 E, EPB);
    fine_kernel<<<NB, 512, 0, stream>>>(tmp, bucketBase, offs, edges, dinv, N,
                                        E, NB);

    // ---- layer 1: hA = bf16(dinv * (x @ W1)); hB = dinv*(A_ew hA + hA) ----
    gemm_mfma_kernel<128, 64, false, false, false>
        <<<nb_g, 256, 0, stream>>>(x, W1T, nullptr, dinv, hA, N);
    agg64_kernel<<<nb_a, 256, 0, stream>>>(hA, edges, offs, dinv, hB, N);

    // ---- layer 2 ----
    gemm_mfma_kernel<64, 64, true, true, true>
        <<<nb_g, 256, 0, stream>>>(hB, W2T, b1, dinv, hA, N);
    agg64_kernel<<<nb_a, 256, 0, stream>>>(hA, edges, offs, dinv, hB, N);

    // ---- layer 3: out = dinv*(A_ew hA3 + hA3) + b3; mean pool ----
    gemm_mfma_kernel<64, 32, true, true, true>
        <<<nb_g, 256, 0, stream>>>(hB, W3T, b2, dinv, hA, N);
    agg32_final_kernel<<<nb_a, 256, 0, stream>>>(hA, edges, offs, dinv, b3,
                                                 out, mean, N);

    // ---- epilogue: fold mean buckets ----
    write_mean_kernel<<<1, 32, 0, stream>>>(mean, out + (size_t)N * 32,
                                            1.0f / (float)N);
}

// Round 10
// 296.268 us; speedup vs baseline: 2.8028x; 2.8028x over previous
//
#include <hip/hip_runtime.h>

// ---------------------------------------------------------------------------
// GCN 3-layer forward on MI355X — radix CSR build + bf16 MFMA GEMMs with
// dinv folded into the GEMM epilogue (hA = dinv * (xW)), so aggregation is
// out[d] = dinv[d] * (sum_e ew*hA[src] + hA[d])  — norm pass ELIMINATED.
// R18: REVERT to R14 (best measured, 289.2) + agg32_final unroll 4->8
// (32 edges/iter: one latency window per wave instead of two; 8 gathers in
// flight matching agg64; ~+30 VGPR -> ~7 blocks/CU, favorable by R11's
// in-flight = unroll x resident-waves product rule).
// R15/R17 LESSON (measured 557us passB): contended SAME-ADDRESS global
// atomicAdd does NOT pipeline in L2 — ~280 cy serialized each. The
// histG/block_offs private-cursor machinery is what makes passB fast; it is
// NOT dead weight. (Distinct from R4/R5's scattered-sector atomic lesson.)
// R14: bucket totals via per-block global atomics from passA; W transposes
// folded into passA blocks 0..13. R13 LESSON: single-block fused reduce
// re-created R9 latency-starvation. R12: agg = 16 nodes/block-of-256, edge
// segment staged in LDS, deep-unrolled slot chains, predicated tail.
// R11 LESSON: in-flight = unroll x resident waves. R9 LESSON: edge-centric
// LDS-atomic agg 9x worse. R8: agg FETCH insensitive to edge payload bytes.
// ---------------------------------------------------------------------------

typedef unsigned int uint32;
typedef __attribute__((ext_vector_type(8))) short bf16x8;
typedef __attribute__((ext_vector_type(4))) float f32x4;

#define G 256          // blocks in pass A / pass B
#define MAXB 512       // max coarse buckets (256-node buckets, N <= 131072)
#define ECAP 1024      // staged edges per agg block (8 KB LDS)

__device__ __forceinline__ ushort f2bf(float v) {
    uint32 u = __float_as_uint(v);
    u += 0x7fff + ((u >> 16) & 1);  // round to nearest even
    return (ushort)(u >> 16);
}
__device__ __forceinline__ uint32 pack2bf(float a, float b) {
    return (uint32)f2bf(a) | ((uint32)f2bf(b) << 16);
}
__device__ __forceinline__ float bf_lo(uint32 u) {
    return __uint_as_float(u << 16);
}
__device__ __forceinline__ float bf_hi(uint32 u) {
    return __uint_as_float(u & 0xffff0000u);
}

// ---- pass A: per-block LDS histogram over 256-node coarse buckets,
// + global-atomic bucket totals, + W transposes (first 14 blocks) ----
__global__ __launch_bounds__(1024) void passA_hist_kernel(
    const int* __restrict__ dst, int* __restrict__ histG,
    int* __restrict__ totals,
    const float* __restrict__ W1, const float* __restrict__ W2,
    const float* __restrict__ W3, ushort* __restrict__ W1T,
    ushort* __restrict__ W2T, ushort* __restrict__ W3T, int E, int EPB) {
    __shared__ int h[MAXB];
    const int tid = threadIdx.x, g = blockIdx.x;
    // ---- folded W transposes: 14336 elems on blocks 0..13 ----
    int gi = g * 1024 + tid;
    if (gi < 8192) {                      // W1: 128x64
        int k = gi / 64, m = gi % 64;
        W1T[m * 128 + k] = f2bf(W1[gi]);
    } else if (gi < 12288) {              // W2: 64x64
        int j = gi - 8192, k = j / 64, m = j % 64;
        W2T[m * 64 + k] = f2bf(W2[j]);
    } else if (gi < 14336) {              // W3: 64x32
        int j = gi - 12288, k = j / 32, m = j % 32;
        W3T[m * 64 + k] = f2bf(W3[j]);
    }
    if (tid < MAXB) h[tid] = 0;
    __syncthreads();
    const int e0 = g * EPB, e1 = min(e0 + EPB, E);
    for (int e = e0 + tid; e < e1; e += 1024) atomicAdd(&h[dst[e] >> 8], 1);
    __syncthreads();
    if (tid < MAXB) {
        histG[tid * G + g] = h[tid];  // layout [bucket][block]
        if (h[tid] > 0) atomicAdd(&totals[tid], h[tid]);
    }
}

// ---- exclusive scan over bucket totals -> bucketBase[NB+1] (1 block) ----
__global__ __launch_bounds__(512) void bucket_scan_kernel(
    const int* __restrict__ totals, int* __restrict__ bucketBase, int NB,
    int E) {
    __shared__ int s[512];
    const int t = threadIdx.x;
    int v = (t < NB) ? totals[t] : 0;
    s[t] = v;
    __syncthreads();
    for (int off = 1; off < 512; off <<= 1) {
        int u = (t >= off) ? s[t - off] : 0;
        __syncthreads();
        s[t] += u;
        __syncthreads();
    }
    if (t < NB) bucketBase[t] = s[t] - v;  // exclusive
    if (t == 0) bucketBase[NB] = E;
}

// ---- per-(bucket,block) write offsets: scan histG row along blocks ----
__global__ __launch_bounds__(256) void block_offs_kernel(
    const int* __restrict__ histG, const int* __restrict__ bucketBase,
    int* __restrict__ blockOffs) {
    __shared__ int s[G];
    const int b = blockIdx.x, g = threadIdx.x;
    int v = histG[b * G + g];
    s[g] = v;
    __syncthreads();
    for (int off = 1; off < G; off <<= 1) {
        int u = (g >= off) ? s[g - off] : 0;
        __syncthreads();
        s[g] += u;
        __syncthreads();
    }
    blockOffs[b * G + g] = bucketBase[b] + s[g] - v;  // exclusive along g
}

// ---- pass B: scatter edges to their coarse-bucket segment (LDS cursors) ----
__global__ __launch_bounds__(1024) void passB_scatter_kernel(
    const int* __restrict__ src, const int* __restrict__ dst,
    const float* __restrict__ ew, const int* __restrict__ blockOffs,
    int2* __restrict__ tmp, int E, int EPB, int NB) {
    __shared__ int cur[MAXB];
    const int tid = threadIdx.x, g = blockIdx.x;
    if (tid < MAXB) cur[tid] = (tid < NB) ? blockOffs[tid * G + g] : 0;
    __syncthreads();
    const int e0 = g * EPB, e1 = min(e0 + EPB, E);
    for (int e = e0 + tid; e < e1; e += 1024) {
        int d = dst[e];
        int b = d >> 8;
        int pos = atomicAdd(&cur[b], 1);  // LDS atomic (private cursor)
        // pack: src (17 bits) | local-dst (8 bits) << 17 ; .y = ew bits
        tmp[pos] = make_int2(src[e] | ((d & 255) << 17),
                             __float_as_int(ew[e]));
    }
}

// ---- fine: per-bucket LDS counting sort -> edges(src|ldst,ew) + offs + dinv
__global__ __launch_bounds__(512) void fine_kernel(
    const int2* __restrict__ tmp, const int* __restrict__ bucketBase,
    int* __restrict__ offs, int2* __restrict__ edges,
    float* __restrict__ dinv, int N, int E, int NB) {
    __shared__ int cnt[256];
    __shared__ int pos0[256];
    __shared__ float degf[256];
    const int t = threadIdx.x, b = blockIdx.x;
    const int base = bucketBase[b], endb = bucketBase[b + 1];
    if (t < 256) { cnt[t] = 0; degf[t] = 0.0f; }
    __syncthreads();
    for (int j = base + t; j < endb; j += 512)
        atomicAdd(&cnt[(tmp[j].x >> 17) & 255], 1);
    __syncthreads();
    int v = 0;
    if (t < 256) { v = cnt[t]; pos0[t] = v; }
    __syncthreads();
    for (int off = 1; off < 256; off <<= 1) {  // Hillis-Steele
        int u = 0;
        if (t < 256 && t >= off) u = pos0[t - off];
        __syncthreads();
        if (t < 256) pos0[t] += u;
        __syncthreads();
    }
    if (t < 256) { pos0[t] -= v; cnt[t] = 0; }  // exclusive; reset cursors
    __syncthreads();
    const int node = (b << 8) + t;
    if (t < 256 && node < N) offs[node] = base + pos0[t];
    if (b == NB - 1 && t == 0) offs[N] = E;
    for (int j = base + t; j < endb; j += 512) {
        int2 ed = tmp[j];
        int ldst = (ed.x >> 17) & 255;
        int p = base + pos0[ldst] + atomicAdd(&cnt[ldst], 1);
        edges[p] = ed;  // keep packed local-dst bits (harmless; agg masks)
        atomicAdd(&degf[ldst], __int_as_float(ed.y));  // LDS float atomic
    }
    __syncthreads();
    if (t < 256 && node < N) dinv[node] = rsqrtf(1.0f + degf[t]);
}

// ---- MFMA GEMM: out_bf16[n] = dinv[n] * (f(in[n]) @ W).  4 waves x 16-row
// tile, v_mfma_f32_16x16x32_bf16; LDS rows padded +8 bf16. m89 layouts. ----
template <int K, int M, bool RELU, bool BIAS, bool INBF16>
__global__ __launch_bounds__(256) void gemm_mfma_kernel(
    const void* __restrict__ in_, const ushort* __restrict__ WT,
    const float* __restrict__ bias_in, const float* __restrict__ dinv,
    ushort* __restrict__ out, int N) {
    constexpr int KP = K + 8;    // padded LDS row stride (bf16 units)
    constexpr int CCH = M / 16;  // col chunks
    __shared__ __align__(16) ushort Xl[64 * KP];
    __shared__ __align__(16) ushort Wl[M * KP];
    const int tid = threadIdx.x;
    const int node0 = blockIdx.x * 64;

    for (int i = tid; i < M * (K / 8); i += 256) {
        int row = i / (K / 8), kc = i % (K / 8);
        uint4 u = ((const uint4*)WT)[i];
        *(uint4*)&Wl[row * KP + kc * 8] = u;
    }
    if (INBF16) {
        for (int i = tid; i < 64 * (K / 8); i += 256) {
            int row = i / (K / 8), kc = i % (K / 8);
            int node = node0 + row;
            uint4 u = make_uint4(0, 0, 0, 0);
            if (node < N) {
                u = ((const uint4*)in_)[(size_t)node * (K / 8) + kc];
                if (BIAS || RELU) {
                    float v[8];
                    v[0] = bf_lo(u.x); v[1] = bf_hi(u.x);
                    v[2] = bf_lo(u.y); v[3] = bf_hi(u.y);
                    v[4] = bf_lo(u.z); v[5] = bf_hi(u.z);
                    v[6] = bf_lo(u.w); v[7] = bf_hi(u.w);
#pragma unroll
                    for (int j = 0; j < 8; ++j) {
                        if (BIAS) v[j] += bias_in[kc * 8 + j];
                        if (RELU) v[j] = fmaxf(v[j], 0.f);
                    }
                    u.x = pack2bf(v[0], v[1]); u.y = pack2bf(v[2], v[3]);
                    u.z = pack2bf(v[4], v[5]); u.w = pack2bf(v[6], v[7]);
                }
            }
            *(uint4*)&Xl[row * KP + kc * 8] = u;
        }
    } else {
        for (int i = tid; i < 64 * (K / 4); i += 256) {
            int row = i / (K / 4), kc = i % (K / 4);
            int node = node0 + row;
            uint2 p = make_uint2(0, 0);
            if (node < N) {
                float4 v = ((const float4*)in_)[(size_t)node * (K / 4) + kc];
                p.x = pack2bf(v.x, v.y);
                p.y = pack2bf(v.z, v.w);
            }
            *(uint2*)&Xl[row * KP + kc * 4] = p;
        }
    }
    __syncthreads();

    const int wv = tid >> 6, lane = tid & 63;
    const int r16 = lane & 15, quad = lane >> 4;
    f32x4 acc[CCH];
#pragma unroll
    for (int c = 0; c < CCH; ++c) acc[c] = (f32x4){0.f, 0.f, 0.f, 0.f};
#pragma unroll
    for (int kq = 0; kq < K / 32; ++kq) {
        bf16x8 a = *(const bf16x8*)
            &Xl[(wv * 16 + r16) * KP + kq * 32 + quad * 8];
#pragma unroll
        for (int c = 0; c < CCH; ++c) {
            bf16x8 b = *(const bf16x8*)
                &Wl[(c * 16 + r16) * KP + kq * 32 + quad * 8];
            acc[c] = __builtin_amdgcn_mfma_f32_16x16x32_bf16(a, b, acc[c],
                                                             0, 0, 0);
        }
    }
    // D: col = lane&15, row = quad*4 + reg; scale row by dinv[node]
#pragma unroll
    for (int r = 0; r < 4; ++r) {
        int node = node0 + wv * 16 + quad * 4 + r;
        float dv = (node < N) ? dinv[node] : 0.f;
#pragma unroll
        for (int c = 0; c < CCH; ++c) {
            if (node < N)
                out[(size_t)node * M + c * 16 + r16] = f2bf(acc[c][r] * dv);
        }
    }
}

// ---- CSR aggregate, 64-wide bf16 rows (128 B). 16 nodes/block, 16-lane
// node group (8 r-lanes x 2 slots). Block edge segment staged in LDS; slot
// chain unrolled x8 -> degree-16 node done in ONE iteration, 8 gathers in
// flight. Predicated tail -> row 0 (L1-hot), weight 0. out = dinv*(acc+self).
__global__ __launch_bounds__(256) void agg64_kernel(
    const ushort* __restrict__ h, const int2* __restrict__ edges,
    const int* __restrict__ offs, const float* __restrict__ dinv,
    ushort* __restrict__ out, int N) {
    __shared__ int soffs[17];
    __shared__ float sdinv[16];
    __shared__ int2 eLds[ECAP];
    const int tid = threadIdx.x;
    const int n0 = blockIdx.x * 16;
    if (tid < 17) soffs[tid] = offs[min(n0 + tid, N)];
    if (tid < 16) sdinv[tid] = (n0 + tid < N) ? dinv[n0 + tid] : 0.0f;
    __syncthreads();
    const int eBase = soffs[0];
    const int eTot = soffs[16] - eBase;
    for (int i = tid; i < min(eTot, ECAP); i += 256)
        eLds[i] = edges[eBase + i];

    const int lane = tid & 63, wv = tid >> 6;
    const int r = lane & 7;           // uint4 index within the 128 B row
    const int slot = (lane >> 3) & 1; // 2 edge slots per node
    const int li = wv * 4 + (lane >> 4);  // local node 0..15
    const int node = n0 + li;
    const uint4* __restrict__ h4 = (const uint4*)h;

    // self row issued before the staging barrier — overlaps it
    uint4 hv = make_uint4(0u, 0u, 0u, 0u);
    if (slot == 0 && node < N) hv = h4[(size_t)node * 8 + r];
    __syncthreads();

    const int start = soffs[li], end = soffs[li + 1];
    float acc[8] = {};
    if (eTot <= ECAP) {  // fast path: edges from LDS
        for (int j = start + slot; j < end; j += 16) {
            int2 e[8];
            uint4 u[8];
#pragma unroll
            for (int k = 0; k < 8; ++k) {
                int idx = j + 2 * k;
                e[k] = (idx < end) ? eLds[idx - eBase] : make_int2(0, 0);
            }
#pragma unroll
            for (int k = 0; k < 8; ++k)
                u[k] = h4[(size_t)(e[k].x & 0x1FFFF) * 8 + r];
#pragma unroll
            for (int k = 0; k < 8; ++k) {
                float w = __int_as_float(e[k].y);
                acc[0] += bf_lo(u[k].x) * w; acc[1] += bf_hi(u[k].x) * w;
                acc[2] += bf_lo(u[k].y) * w; acc[3] += bf_hi(u[k].y) * w;
                acc[4] += bf_lo(u[k].z) * w; acc[5] += bf_hi(u[k].z) * w;
                acc[6] += bf_lo(u[k].w) * w; acc[7] += bf_hi(u[k].w) * w;
            }
        }
    } else {  // overflow fallback: edges straight from global (block-uniform)
        for (int j = start + slot; j < end; j += 16) {
            int2 e[8];
            uint4 u[8];
#pragma unroll
            for (int k = 0; k < 8; ++k) {
                int idx = j + 2 * k;
                e[k] = (idx < end) ? edges[idx] : make_int2(0, 0);
            }
#pragma unroll
            for (int k = 0; k < 8; ++k)
                u[k] = h4[(size_t)(e[k].x & 0x1FFFF) * 8 + r];
#pragma unroll
            for (int k = 0; k < 8; ++k) {
                float w = __int_as_float(e[k].y);
                acc[0] += bf_lo(u[k].x) * w; acc[1] += bf_hi(u[k].x) * w;
                acc[2] += bf_lo(u[k].y) * w; acc[3] += bf_hi(u[k].y) * w;
                acc[4] += bf_lo(u[k].z) * w; acc[5] += bf_hi(u[k].z) * w;
                acc[6] += bf_lo(u[k].w) * w; acc[7] += bf_hi(u[k].w) * w;
            }
        }
    }
#pragma unroll
    for (int k = 0; k < 8; ++k) acc[k] += __shfl_xor(acc[k], 8);
    if (slot == 0 && node < N) {
        float sc = sdinv[li];
        uint4 o;
        o.x = pack2bf((acc[0] + bf_lo(hv.x)) * sc, (acc[1] + bf_hi(hv.x)) * sc);
        o.y = pack2bf((acc[2] + bf_lo(hv.y)) * sc, (acc[3] + bf_hi(hv.y)) * sc);
        o.z = pack2bf((acc[4] + bf_lo(hv.z)) * sc, (acc[5] + bf_hi(hv.z)) * sc);
        o.w = pack2bf((acc[6] + bf_lo(hv.w)) * sc, (acc[7] + bf_hi(hv.w)) * sc);
        ((uint4*)out)[(size_t)node * 8 + r] = o;
    }
}

// ---- CSR aggregate, 32-wide bf16 rows (64 B), final layer. 16 nodes/block,
// 16-lane node group (4 r-lanes x 4 slots). LDS-staged edges; chain unrolled
// x8 (R18: was x4) -> 32 edges/iter, ONE latency window per wave, 8 gathers
// in flight. out = dinv*(acc+self) + b3, fp32; block mean -> spread buckets.
__global__ __launch_bounds__(256) void agg32_final_kernel(
    const ushort* __restrict__ h, const int2* __restrict__ edges,
    const int* __restrict__ offs, const float* __restrict__ dinv,
    const float* __restrict__ b3, float* __restrict__ out,
    float* __restrict__ mean_acc, int N) {
    __shared__ int soffs[17];
    __shared__ float sdinv[16];
    __shared__ float ssum[32];
    __shared__ int2 eLds[ECAP];
    const int tid = threadIdx.x;
    const int n0 = blockIdx.x * 16;
    if (tid < 17) soffs[tid] = offs[min(n0 + tid, N)];
    if (tid < 16) sdinv[tid] = (n0 + tid < N) ? dinv[n0 + tid] : 0.0f;
    if (tid < 32) ssum[tid] = 0.0f;
    __syncthreads();
    const int eBase = soffs[0];
    const int eTot = soffs[16] - eBase;
    for (int i = tid; i < min(eTot, ECAP); i += 256)
        eLds[i] = edges[eBase + i];

    const int lane = tid & 63, wv = tid >> 6;
    const int r = lane & 3;           // uint4 index within the 64 B row
    const int slot = (lane >> 2) & 3; // 4 edge slots per node
    const int li = wv * 4 + (lane >> 4);  // local node 0..15
    const int node = n0 + li;
    const uint4* __restrict__ h4 = (const uint4*)h;

    uint4 hv = make_uint4(0u, 0u, 0u, 0u);
    if (slot == 0 && node < N) hv = h4[(size_t)node * 4 + r];
    __syncthreads();

    const int start = soffs[li], end = soffs[li + 1];
    float acc[8] = {};
    if (eTot <= ECAP) {  // fast path: edges from LDS
        for (int j = start + slot; j < end; j += 32) {
            int2 e[8];
            uint4 u[8];
#pragma unroll
            for (int k = 0; k < 8; ++k) {
                int idx = j + 4 * k;
                e[k] = (idx < end) ? eLds[idx - eBase] : make_int2(0, 0);
            }
#pragma unroll
            for (int k = 0; k < 8; ++k)
                u[k] = h4[(size_t)(e[k].x & 0x1FFFF) * 4 + r];
#pragma unroll
            for (int k = 0; k < 8; ++k) {
                float w = __int_as_float(e[k].y);
                acc[0] += bf_lo(u[k].x) * w; acc[1] += bf_hi(u[k].x) * w;
                acc[2] += bf_lo(u[k].y) * w; acc[3] += bf_hi(u[k].y) * w;
                acc[4] += bf_lo(u[k].z) * w; acc[5] += bf_hi(u[k].z) * w;
                acc[6] += bf_lo(u[k].w) * w; acc[7] += bf_hi(u[k].w) * w;
            }
        }
    } else {  // overflow fallback (block-uniform)
        for (int j = start + slot; j < end; j += 32) {
            int2 e[8];
            uint4 u[8];
#pragma unroll
            for (int k = 0; k < 8; ++k) {
                int idx = j + 4 * k;
                e[k] = (idx < end) ? edges[idx] : make_int2(0, 0);
            }
#pragma unroll
            for (int k = 0; k < 8; ++k)
                u[k] = h4[(size_t)(e[k].x & 0x1FFFF) * 4 + r];
#pragma unroll
            for (int k = 0; k < 8; ++k) {
                float w = __int_as_float(e[k].y);
                acc[0] += bf_lo(u[k].x) * w; acc[1] += bf_hi(u[k].x) * w;
                acc[2] += bf_lo(u[k].y) * w; acc[3] += bf_hi(u[k].y) * w;
                acc[4] += bf_lo(u[k].z) * w; acc[5] += bf_hi(u[k].z) * w;
                acc[6] += bf_lo(u[k].w) * w; acc[7] += bf_hi(u[k].w) * w;
            }
        }
    }
#pragma unroll
    for (int k = 0; k < 8; ++k) {
        acc[k] += __shfl_xor(acc[k], 4);
        acc[k] += __shfl_xor(acc[k], 8);
    }
    if (slot == 0 && node < N) {
        float sc = sdinv[li];
        const float4* b34 = (const float4*)b3;
        float4 bA = b34[r * 2], bB = b34[r * 2 + 1];
        float4 o0, o1;
        o0.x = (acc[0] + bf_lo(hv.x)) * sc + bA.x;
        o0.y = (acc[1] + bf_hi(hv.x)) * sc + bA.y;
        o0.z = (acc[2] + bf_lo(hv.y)) * sc + bA.z;
        o0.w = (acc[3] + bf_hi(hv.y)) * sc + bA.w;
        o1.x = (acc[4] + bf_lo(hv.z)) * sc + bB.x;
        o1.y = (acc[5] + bf_hi(hv.z)) * sc + bB.y;
        o1.z = (acc[6] + bf_lo(hv.w)) * sc + bB.z;
        o1.w = (acc[7] + bf_hi(hv.w)) * sc + bB.w;
        ((float4*)out)[(size_t)node * 8 + r * 2] = o0;
        ((float4*)out)[(size_t)node * 8 + r * 2 + 1] = o1;
        int fb = r * 8;
        atomicAdd(&ssum[fb + 0], o0.x); atomicAdd(&ssum[fb + 1], o0.y);
        atomicAdd(&ssum[fb + 2], o0.z); atomicAdd(&ssum[fb + 3], o0.w);
        atomicAdd(&ssum[fb + 4], o1.x); atomicAdd(&ssum[fb + 5], o1.y);
        atomicAdd(&ssum[fb + 6], o1.z); atomicAdd(&ssum[fb + 7], o1.w);
    }
    __syncthreads();
    if (tid < 32) {
        int bucket = blockIdx.x & 127;  // spread-bucket mean (R2 lesson)
        atomicAdd(&mean_acc[bucket * 32 + tid], ssum[tid]);
    }
}

__global__ void write_mean_kernel(const float* __restrict__ mean_acc,
                                  float* __restrict__ out_tail, float invN) {
    int f = threadIdx.x;
    if (f < 32) {
        float s = 0.0f;
        for (int b = 0; b < 128; ++b) s += mean_acc[b * 32 + f];
        out_tail[f] = s * invN;
    }
}

extern "C" void kernel_launch(void* const* d_in, const int* in_sizes, int n_in,
                              void* d_out, int out_size, void* d_ws,
                              size_t ws_size, hipStream_t stream) {
    const float* x  = (const float*)d_in[0];
    const int*   ei = (const int*)d_in[1];
    const float* ew = (const float*)d_in[2];
    const float* W1 = (const float*)d_in[3];
    const float* b1 = (const float*)d_in[4];
    const float* W2 = (const float*)d_in[5];
    const float* b2 = (const float*)d_in[6];
    const float* W3 = (const float*)d_in[7];
    const float* b3 = (const float*)d_in[8];

    const int N = in_sizes[0] / 128;
    const int E = in_sizes[1] / 2;
    const int* src = ei;
    const int* dst = ei + E;

    const int NB = (N + 255) >> 8;          // 256-node coarse buckets
    const int EPB = (E + G - 1) / G;        // edges per pass-A/B block

    float* out = (float*)d_out;
    char* wsp = (char*)d_ws;
    auto carve = [&](size_t bytes) {
        char* p = wsp;
        wsp += (bytes + 255) & ~(size_t)255;
        return p;
    };
    float*  dinv       = (float*)carve((size_t)N * 4);
    int*    offs       = (int*)carve((size_t)(N + 1) * 4);
    int*    bucketBase = (int*)carve((MAXB + 1) * 4);
    float*  mean       = (float*)carve(128 * 32 * 4);   // 16384 B
    int*    totals     = (int*)carve(MAXB * 4);         // contiguous w/ mean
    int*    histG      = (int*)carve((size_t)MAXB * G * 4);
    int*    blockOffs  = (int*)carve((size_t)MAXB * G * 4);
    int2*   tmp        = (int2*)carve((size_t)E * 8);
    int2*   edges      = (int2*)carve((size_t)E * 8);
    ushort* hA         = (ushort*)carve((size_t)N * 64 * 2);
    ushort* hB         = (ushort*)carve((size_t)N * 64 * 2);
    ushort* W1T        = (ushort*)carve(128 * 64 * 2);
    ushort* W2T        = (ushort*)carve(64 * 64 * 2);
    ushort* W3T        = (ushort*)carve(64 * 32 * 2);

    const int nb_a = (N + 15) / 16;  // agg kernels: 16 nodes per 256-block
    const int nb_g = (N + 63) / 64;  // MFMA gemm: 64 nodes/block

    // one memset covers mean (16384 B) + totals (2048 B), carved contiguous
    hipMemsetAsync(mean, 0, 128 * 32 * 4 + MAXB * 4, stream);

    // ---- CSR build: LDS hist (+W transposes +totals atomics) -> scan ->
    //      block offs -> bucket scatter -> fine counting sort ----
    passA_hist_kernel<<<G, 1024, 0, stream>>>(dst, histG, totals, W1, W2, W3,
                                              W1T, W2T, W3T, E, EPB);
    bucket_scan_kernel<<<1, 512, 0, stream>>>(totals, bucketBase, NB, E);
    block_offs_kernel<<<NB, G, 0, stream>>>(histG, bucketBase, blockOffs);
    passB_scatter_kernel<<<G, 1024, 0, stream>>>(src, dst, ew, blockOffs, tmp,
                                                 E, EPB, NB);
    fine_kernel<<<NB, 512, 0, stream>>>(tmp, bucketBase, offs, edges, dinv, N,
                                        E, NB);

    // ---- layer 1: hA = bf16(dinv * (x @ W1)); hB = dinv*(A_ew hA + hA) ----
    gemm_mfma_kernel<128, 64, false, false, false>
        <<<nb_g, 256, 0, stream>>>(x, W1T, nullptr, dinv, hA, N);
    agg64_kernel<<<nb_a, 256, 0, stream>>>(hA, edges, offs, dinv, hB, N);

    // ---- layer 2 ----
    gemm_mfma_kernel<64, 64, true, true, true>
        <<<nb_g, 256, 0, stream>>>(hB, W2T, b1, dinv, hA, N);
    agg64_kernel<<<nb_a, 256, 0, stream>>>(hA, edges, offs, dinv, hB, N);

    // ---- layer 3: out = dinv*(A_ew hA3 + hA3) + b3; mean pool ----
    gemm_mfma_kernel<64, 32, true, true, true>
        <<<nb_g, 256, 0, stream>>>(hB, W3T, b2, dinv, hA, N);
    agg32_final_kernel<<<nb_a, 256, 0, stream>>>(hA, edges, offs, dinv, b3,
                                                 out, mean, N);

    // ---- epilogue: fold mean buckets ----
    write_mean_kernel<<<1, 32, 0, stream>>>(mean, out + (size_t)N * 32,
                                            1.0f / (float)N);
}

// Round 11
// 289.144 us; speedup vs baseline: 2.8719x; 1.0246x over previous
//
#include <hip/hip_runtime.h>

// ---------------------------------------------------------------------------
// GCN 3-layer forward on MI355X — radix CSR build + bf16 MFMA GEMMs with
// dinv folded into the GEMM epilogue (hA = dinv * (xW)), so aggregation is
// out[d] = dinv[d] * (sum_e ew*hA[src] + hA[d])  — norm pass ELIMINATED.
// R19: REVERT to R14 exactly (best measured, 289.2us). R18 LESSON: agg32
// unroll 4->8 regressed 7us — with mean deg 16 and 4 slots, 32-edge batches
// are ~50% predicated dummies; refined rule: in-flight = unroll x resident
// waves x USEFUL FRACTION; unroll past mean-deg/slots buys dummy work.
// R15/R17 LESSON (measured 557us passB): contended SAME-ADDRESS global
// atomicAdd does NOT pipeline in L2 — ~280 cy serialized each; the
// histG/block_offs private-cursor machinery is what makes passB fast.
// R14: bucket totals via per-block global atomics from passA; W transposes
// folded into passA blocks 0..13. R13 LESSON: single-block fused reduce
// re-created R9 latency-starvation. R12: agg = 16 nodes/block-of-256, edge
// segment staged in LDS, deep-unrolled slot chains, predicated tail.
// R11 LESSON: in-flight = unroll x resident waves. R9 LESSON: edge-centric
// LDS-atomic agg 9x worse. R8: agg FETCH insensitive to edge payload bytes.
// Session: 342.5 -> 289 us; structural latency plateau (no kernel at a
// counter-visible pipe ceiling; serial 12-dispatch dependency chain).
// ---------------------------------------------------------------------------

typedef unsigned int uint32;
typedef __attribute__((ext_vector_type(8))) short bf16x8;
typedef __attribute__((ext_vector_type(4))) float f32x4;

#define G 256          // blocks in pass A / pass B
#define MAXB 512       // max coarse buckets (256-node buckets, N <= 131072)
#define ECAP 1024      // staged edges per agg block (8 KB LDS)

__device__ __forceinline__ ushort f2bf(float v) {
    uint32 u = __float_as_uint(v);
    u += 0x7fff + ((u >> 16) & 1);  // round to nearest even
    return (ushort)(u >> 16);
}
__device__ __forceinline__ uint32 pack2bf(float a, float b) {
    return (uint32)f2bf(a) | ((uint32)f2bf(b) << 16);
}
__device__ __forceinline__ float bf_lo(uint32 u) {
    return __uint_as_float(u << 16);
}
__device__ __forceinline__ float bf_hi(uint32 u) {
    return __uint_as_float(u & 0xffff0000u);
}

// ---- pass A: per-block LDS histogram over 256-node coarse buckets,
// + global-atomic bucket totals, + W transposes (first 14 blocks) ----
__global__ __launch_bounds__(1024) void passA_hist_kernel(
    const int* __restrict__ dst, int* __restrict__ histG,
    int* __restrict__ totals,
    const float* __restrict__ W1, const float* __restrict__ W2,
    const float* __restrict__ W3, ushort* __restrict__ W1T,
    ushort* __restrict__ W2T, ushort* __restrict__ W3T, int E, int EPB) {
    __shared__ int h[MAXB];
    const int tid = threadIdx.x, g = blockIdx.x;
    // ---- folded W transposes: 14336 elems on blocks 0..13 ----
    int gi = g * 1024 + tid;
    if (gi < 8192) {                      // W1: 128x64
        int k = gi / 64, m = gi % 64;
        W1T[m * 128 + k] = f2bf(W1[gi]);
    } else if (gi < 12288) {              // W2: 64x64
        int j = gi - 8192, k = j / 64, m = j % 64;
        W2T[m * 64 + k] = f2bf(W2[j]);
    } else if (gi < 14336) {              // W3: 64x32
        int j = gi - 12288, k = j / 32, m = j % 32;
        W3T[m * 64 + k] = f2bf(W3[j]);
    }
    if (tid < MAXB) h[tid] = 0;
    __syncthreads();
    const int e0 = g * EPB, e1 = min(e0 + EPB, E);
    for (int e = e0 + tid; e < e1; e += 1024) atomicAdd(&h[dst[e] >> 8], 1);
    __syncthreads();
    if (tid < MAXB) {
        histG[tid * G + g] = h[tid];  // layout [bucket][block]
        if (h[tid] > 0) atomicAdd(&totals[tid], h[tid]);
    }
}

// ---- exclusive scan over bucket totals -> bucketBase[NB+1] (1 block) ----
__global__ __launch_bounds__(512) void bucket_scan_kernel(
    const int* __restrict__ totals, int* __restrict__ bucketBase, int NB,
    int E) {
    __shared__ int s[512];
    const int t = threadIdx.x;
    int v = (t < NB) ? totals[t] : 0;
    s[t] = v;
    __syncthreads();
    for (int off = 1; off < 512; off <<= 1) {
        int u = (t >= off) ? s[t - off] : 0;
        __syncthreads();
        s[t] += u;
        __syncthreads();
    }
    if (t < NB) bucketBase[t] = s[t] - v;  // exclusive
    if (t == 0) bucketBase[NB] = E;
}

// ---- per-(bucket,block) write offsets: scan histG row along blocks ----
__global__ __launch_bounds__(256) void block_offs_kernel(
    const int* __restrict__ histG, const int* __restrict__ bucketBase,
    int* __restrict__ blockOffs) {
    __shared__ int s[G];
    const int b = blockIdx.x, g = threadIdx.x;
    int v = histG[b * G + g];
    s[g] = v;
    __syncthreads();
    for (int off = 1; off < G; off <<= 1) {
        int u = (g >= off) ? s[g - off] : 0;
        __syncthreads();
        s[g] += u;
        __syncthreads();
    }
    blockOffs[b * G + g] = bucketBase[b] + s[g] - v;  // exclusive along g
}

// ---- pass B: scatter edges to their coarse-bucket segment (LDS cursors) ----
__global__ __launch_bounds__(1024) void passB_scatter_kernel(
    const int* __restrict__ src, const int* __restrict__ dst,
    const float* __restrict__ ew, const int* __restrict__ blockOffs,
    int2* __restrict__ tmp, int E, int EPB, int NB) {
    __shared__ int cur[MAXB];
    const int tid = threadIdx.x, g = blockIdx.x;
    if (tid < MAXB) cur[tid] = (tid < NB) ? blockOffs[tid * G + g] : 0;
    __syncthreads();
    const int e0 = g * EPB, e1 = min(e0 + EPB, E);
    for (int e = e0 + tid; e < e1; e += 1024) {
        int d = dst[e];
        int b = d >> 8;
        int pos = atomicAdd(&cur[b], 1);  // LDS atomic (private cursor)
        // pack: src (17 bits) | local-dst (8 bits) << 17 ; .y = ew bits
        tmp[pos] = make_int2(src[e] | ((d & 255) << 17),
                             __float_as_int(ew[e]));
    }
}

// ---- fine: per-bucket LDS counting sort -> edges(src|ldst,ew) + offs + dinv
__global__ __launch_bounds__(512) void fine_kernel(
    const int2* __restrict__ tmp, const int* __restrict__ bucketBase,
    int* __restrict__ offs, int2* __restrict__ edges,
    float* __restrict__ dinv, int N, int E, int NB) {
    __shared__ int cnt[256];
    __shared__ int pos0[256];
    __shared__ float degf[256];
    const int t = threadIdx.x, b = blockIdx.x;
    const int base = bucketBase[b], endb = bucketBase[b + 1];
    if (t < 256) { cnt[t] = 0; degf[t] = 0.0f; }
    __syncthreads();
    for (int j = base + t; j < endb; j += 512)
        atomicAdd(&cnt[(tmp[j].x >> 17) & 255], 1);
    __syncthreads();
    int v = 0;
    if (t < 256) { v = cnt[t]; pos0[t] = v; }
    __syncthreads();
    for (int off = 1; off < 256; off <<= 1) {  // Hillis-Steele
        int u = 0;
        if (t < 256 && t >= off) u = pos0[t - off];
        __syncthreads();
        if (t < 256) pos0[t] += u;
        __syncthreads();
    }
    if (t < 256) { pos0[t] -= v; cnt[t] = 0; }  // exclusive; reset cursors
    __syncthreads();
    const int node = (b << 8) + t;
    if (t < 256 && node < N) offs[node] = base + pos0[t];
    if (b == NB - 1 && t == 0) offs[N] = E;
    for (int j = base + t; j < endb; j += 512) {
        int2 ed = tmp[j];
        int ldst = (ed.x >> 17) & 255;
        int p = base + pos0[ldst] + atomicAdd(&cnt[ldst], 1);
        edges[p] = ed;  // keep packed local-dst bits (harmless; agg masks)
        atomicAdd(&degf[ldst], __int_as_float(ed.y));  // LDS float atomic
    }
    __syncthreads();
    if (t < 256 && node < N) dinv[node] = rsqrtf(1.0f + degf[t]);
}

// ---- MFMA GEMM: out_bf16[n] = dinv[n] * (f(in[n]) @ W).  4 waves x 16-row
// tile, v_mfma_f32_16x16x32_bf16; LDS rows padded +8 bf16. m89 layouts. ----
template <int K, int M, bool RELU, bool BIAS, bool INBF16>
__global__ __launch_bounds__(256) void gemm_mfma_kernel(
    const void* __restrict__ in_, const ushort* __restrict__ WT,
    const float* __restrict__ bias_in, const float* __restrict__ dinv,
    ushort* __restrict__ out, int N) {
    constexpr int KP = K + 8;    // padded LDS row stride (bf16 units)
    constexpr int CCH = M / 16;  // col chunks
    __shared__ __align__(16) ushort Xl[64 * KP];
    __shared__ __align__(16) ushort Wl[M * KP];
    const int tid = threadIdx.x;
    const int node0 = blockIdx.x * 64;

    for (int i = tid; i < M * (K / 8); i += 256) {
        int row = i / (K / 8), kc = i % (K / 8);
        uint4 u = ((const uint4*)WT)[i];
        *(uint4*)&Wl[row * KP + kc * 8] = u;
    }
    if (INBF16) {
        for (int i = tid; i < 64 * (K / 8); i += 256) {
            int row = i / (K / 8), kc = i % (K / 8);
            int node = node0 + row;
            uint4 u = make_uint4(0, 0, 0, 0);
            if (node < N) {
                u = ((const uint4*)in_)[(size_t)node * (K / 8) + kc];
                if (BIAS || RELU) {
                    float v[8];
                    v[0] = bf_lo(u.x); v[1] = bf_hi(u.x);
                    v[2] = bf_lo(u.y); v[3] = bf_hi(u.y);
                    v[4] = bf_lo(u.z); v[5] = bf_hi(u.z);
                    v[6] = bf_lo(u.w); v[7] = bf_hi(u.w);
#pragma unroll
                    for (int j = 0; j < 8; ++j) {
                        if (BIAS) v[j] += bias_in[kc * 8 + j];
                        if (RELU) v[j] = fmaxf(v[j], 0.f);
                    }
                    u.x = pack2bf(v[0], v[1]); u.y = pack2bf(v[2], v[3]);
                    u.z = pack2bf(v[4], v[5]); u.w = pack2bf(v[6], v[7]);
                }
            }
            *(uint4*)&Xl[row * KP + kc * 8] = u;
        }
    } else {
        for (int i = tid; i < 64 * (K / 4); i += 256) {
            int row = i / (K / 4), kc = i % (K / 4);
            int node = node0 + row;
            uint2 p = make_uint2(0, 0);
            if (node < N) {
                float4 v = ((const float4*)in_)[(size_t)node * (K / 4) + kc];
                p.x = pack2bf(v.x, v.y);
                p.y = pack2bf(v.z, v.w);
            }
            *(uint2*)&Xl[row * KP + kc * 4] = p;
        }
    }
    __syncthreads();

    const int wv = tid >> 6, lane = tid & 63;
    const int r16 = lane & 15, quad = lane >> 4;
    f32x4 acc[CCH];
#pragma unroll
    for (int c = 0; c < CCH; ++c) acc[c] = (f32x4){0.f, 0.f, 0.f, 0.f};
#pragma unroll
    for (int kq = 0; kq < K / 32; ++kq) {
        bf16x8 a = *(const bf16x8*)
            &Xl[(wv * 16 + r16) * KP + kq * 32 + quad * 8];
#pragma unroll
        for (int c = 0; c < CCH; ++c) {
            bf16x8 b = *(const bf16x8*)
                &Wl[(c * 16 + r16) * KP + kq * 32 + quad * 8];
            acc[c] = __builtin_amdgcn_mfma_f32_16x16x32_bf16(a, b, acc[c],
                                                             0, 0, 0);
        }
    }
    // D: col = lane&15, row = quad*4 + reg; scale row by dinv[node]
#pragma unroll
    for (int r = 0; r < 4; ++r) {
        int node = node0 + wv * 16 + quad * 4 + r;
        float dv = (node < N) ? dinv[node] : 0.f;
#pragma unroll
        for (int c = 0; c < CCH; ++c) {
            if (node < N)
                out[(size_t)node * M + c * 16 + r16] = f2bf(acc[c][r] * dv);
        }
    }
}

// ---- CSR aggregate, 64-wide bf16 rows (128 B). 16 nodes/block, 16-lane
// node group (8 r-lanes x 2 slots). Block edge segment staged in LDS; slot
// chain unrolled x8 -> degree-16 node done in ONE iteration, 8 gathers in
// flight. Predicated tail -> row 0 (L1-hot), weight 0. out = dinv*(acc+self).
__global__ __launch_bounds__(256) void agg64_kernel(
    const ushort* __restrict__ h, const int2* __restrict__ edges,
    const int* __restrict__ offs, const float* __restrict__ dinv,
    ushort* __restrict__ out, int N) {
    __shared__ int soffs[17];
    __shared__ float sdinv[16];
    __shared__ int2 eLds[ECAP];
    const int tid = threadIdx.x;
    const int n0 = blockIdx.x * 16;
    if (tid < 17) soffs[tid] = offs[min(n0 + tid, N)];
    if (tid < 16) sdinv[tid] = (n0 + tid < N) ? dinv[n0 + tid] : 0.0f;
    __syncthreads();
    const int eBase = soffs[0];
    const int eTot = soffs[16] - eBase;
    for (int i = tid; i < min(eTot, ECAP); i += 256)
        eLds[i] = edges[eBase + i];

    const int lane = tid & 63, wv = tid >> 6;
    const int r = lane & 7;           // uint4 index within the 128 B row
    const int slot = (lane >> 3) & 1; // 2 edge slots per node
    const int li = wv * 4 + (lane >> 4);  // local node 0..15
    const int node = n0 + li;
    const uint4* __restrict__ h4 = (const uint4*)h;

    // self row issued before the staging barrier — overlaps it
    uint4 hv = make_uint4(0u, 0u, 0u, 0u);
    if (slot == 0 && node < N) hv = h4[(size_t)node * 8 + r];
    __syncthreads();

    const int start = soffs[li], end = soffs[li + 1];
    float acc[8] = {};
    if (eTot <= ECAP) {  // fast path: edges from LDS
        for (int j = start + slot; j < end; j += 16) {
            int2 e[8];
            uint4 u[8];
#pragma unroll
            for (int k = 0; k < 8; ++k) {
                int idx = j + 2 * k;
                e[k] = (idx < end) ? eLds[idx - eBase] : make_int2(0, 0);
            }
#pragma unroll
            for (int k = 0; k < 8; ++k)
                u[k] = h4[(size_t)(e[k].x & 0x1FFFF) * 8 + r];
#pragma unroll
            for (int k = 0; k < 8; ++k) {
                float w = __int_as_float(e[k].y);
                acc[0] += bf_lo(u[k].x) * w; acc[1] += bf_hi(u[k].x) * w;
                acc[2] += bf_lo(u[k].y) * w; acc[3] += bf_hi(u[k].y) * w;
                acc[4] += bf_lo(u[k].z) * w; acc[5] += bf_hi(u[k].z) * w;
                acc[6] += bf_lo(u[k].w) * w; acc[7] += bf_hi(u[k].w) * w;
            }
        }
    } else {  // overflow fallback: edges straight from global (block-uniform)
        for (int j = start + slot; j < end; j += 16) {
            int2 e[8];
            uint4 u[8];
#pragma unroll
            for (int k = 0; k < 8; ++k) {
                int idx = j + 2 * k;
                e[k] = (idx < end) ? edges[idx] : make_int2(0, 0);
            }
#pragma unroll
            for (int k = 0; k < 8; ++k)
                u[k] = h4[(size_t)(e[k].x & 0x1FFFF) * 8 + r];
#pragma unroll
            for (int k = 0; k < 8; ++k) {
                float w = __int_as_float(e[k].y);
                acc[0] += bf_lo(u[k].x) * w; acc[1] += bf_hi(u[k].x) * w;
                acc[2] += bf_lo(u[k].y) * w; acc[3] += bf_hi(u[k].y) * w;
                acc[4] += bf_lo(u[k].z) * w; acc[5] += bf_hi(u[k].z) * w;
                acc[6] += bf_lo(u[k].w) * w; acc[7] += bf_hi(u[k].w) * w;
            }
        }
    }
#pragma unroll
    for (int k = 0; k < 8; ++k) acc[k] += __shfl_xor(acc[k], 8);
    if (slot == 0 && node < N) {
        float sc = sdinv[li];
        uint4 o;
        o.x = pack2bf((acc[0] + bf_lo(hv.x)) * sc, (acc[1] + bf_hi(hv.x)) * sc);
        o.y = pack2bf((acc[2] + bf_lo(hv.y)) * sc, (acc[3] + bf_hi(hv.y)) * sc);
        o.z = pack2bf((acc[4] + bf_lo(hv.z)) * sc, (acc[5] + bf_hi(hv.z)) * sc);
        o.w = pack2bf((acc[6] + bf_lo(hv.w)) * sc, (acc[7] + bf_hi(hv.w)) * sc);
        ((uint4*)out)[(size_t)node * 8 + r] = o;
    }
}

// ---- CSR aggregate, 32-wide bf16 rows (64 B), final layer. 16 nodes/block,
// 16-lane node group (4 r-lanes x 4 slots). LDS-staged edges; chain unrolled
// x4 (R19: reverted from R18's x8 — dummy-gather waste) -> 16 edges/iter,
// 4 gathers in flight. out = dinv*(acc+self) + b3, fp32; block mean ->
// spread buckets. ----
__global__ __launch_bounds__(256) void agg32_final_kernel(
    const ushort* __restrict__ h, const int2* __restrict__ edges,
    const int* __restrict__ offs, const float* __restrict__ dinv,
    const float* __restrict__ b3, float* __restrict__ out,
    float* __restrict__ mean_acc, int N) {
    __shared__ int soffs[17];
    __shared__ float sdinv[16];
    __shared__ float ssum[32];
    __shared__ int2 eLds[ECAP];
    const int tid = threadIdx.x;
    const int n0 = blockIdx.x * 16;
    if (tid < 17) soffs[tid] = offs[min(n0 + tid, N)];
    if (tid < 16) sdinv[tid] = (n0 + tid < N) ? dinv[n0 + tid] : 0.0f;
    if (tid < 32) ssum[tid] = 0.0f;
    __syncthreads();
    const int eBase = soffs[0];
    const int eTot = soffs[16] - eBase;
    for (int i = tid; i < min(eTot, ECAP); i += 256)
        eLds[i] = edges[eBase + i];

    const int lane = tid & 63, wv = tid >> 6;
    const int r = lane & 3;           // uint4 index within the 64 B row
    const int slot = (lane >> 2) & 3; // 4 edge slots per node
    const int li = wv * 4 + (lane >> 4);  // local node 0..15
    const int node = n0 + li;
    const uint4* __restrict__ h4 = (const uint4*)h;

    uint4 hv = make_uint4(0u, 0u, 0u, 0u);
    if (slot == 0 && node < N) hv = h4[(size_t)node * 4 + r];
    __syncthreads();

    const int start = soffs[li], end = soffs[li + 1];
    float acc[8] = {};
    if (eTot <= ECAP) {  // fast path: edges from LDS
        for (int j = start + slot; j < end; j += 16) {
            int2 e[4];
            uint4 u[4];
#pragma unroll
            for (int k = 0; k < 4; ++k) {
                int idx = j + 4 * k;
                e[k] = (idx < end) ? eLds[idx - eBase] : make_int2(0, 0);
            }
#pragma unroll
            for (int k = 0; k < 4; ++k)
                u[k] = h4[(size_t)(e[k].x & 0x1FFFF) * 4 + r];
#pragma unroll
            for (int k = 0; k < 4; ++k) {
                float w = __int_as_float(e[k].y);
                acc[0] += bf_lo(u[k].x) * w; acc[1] += bf_hi(u[k].x) * w;
                acc[2] += bf_lo(u[k].y) * w; acc[3] += bf_hi(u[k].y) * w;
                acc[4] += bf_lo(u[k].z) * w; acc[5] += bf_hi(u[k].z) * w;
                acc[6] += bf_lo(u[k].w) * w; acc[7] += bf_hi(u[k].w) * w;
            }
        }
    } else {  // overflow fallback (block-uniform)
        for (int j = start + slot; j < end; j += 16) {
            int2 e[4];
            uint4 u[4];
#pragma unroll
            for (int k = 0; k < 4; ++k) {
                int idx = j + 4 * k;
                e[k] = (idx < end) ? edges[idx] : make_int2(0, 0);
            }
#pragma unroll
            for (int k = 0; k < 4; ++k)
                u[k] = h4[(size_t)(e[k].x & 0x1FFFF) * 4 + r];
#pragma unroll
            for (int k = 0; k < 4; ++k) {
                float w = __int_as_float(e[k].y);
                acc[0] += bf_lo(u[k].x) * w; acc[1] += bf_hi(u[k].x) * w;
                acc[2] += bf_lo(u[k].y) * w; acc[3] += bf_hi(u[k].y) * w;
                acc[4] += bf_lo(u[k].z) * w; acc[5] += bf_hi(u[k].z) * w;
                acc[6] += bf_lo(u[k].w) * w; acc[7] += bf_hi(u[k].w) * w;
            }
        }
    }
#pragma unroll
    for (int k = 0; k < 8; ++k) {
        acc[k] += __shfl_xor(acc[k], 4);
        acc[k] += __shfl_xor(acc[k], 8);
    }
    if (slot == 0 && node < N) {
        float sc = sdinv[li];
        const float4* b34 = (const float4*)b3;
        float4 bA = b34[r * 2], bB = b34[r * 2 + 1];
        float4 o0, o1;
        o0.x = (acc[0] + bf_lo(hv.x)) * sc + bA.x;
        o0.y = (acc[1] + bf_hi(hv.x)) * sc + bA.y;
        o0.z = (acc[2] + bf_lo(hv.y)) * sc + bA.z;
        o0.w = (acc[3] + bf_hi(hv.y)) * sc + bA.w;
        o1.x = (acc[4] + bf_lo(hv.z)) * sc + bB.x;
        o1.y = (acc[5] + bf_hi(hv.z)) * sc + bB.y;
        o1.z = (acc[6] + bf_lo(hv.w)) * sc + bB.z;
        o1.w = (acc[7] + bf_hi(hv.w)) * sc + bB.w;
        ((float4*)out)[(size_t)node * 8 + r * 2] = o0;
        ((float4*)out)[(size_t)node * 8 + r * 2 + 1] = o1;
        int fb = r * 8;
        atomicAdd(&ssum[fb + 0], o0.x); atomicAdd(&ssum[fb + 1], o0.y);
        atomicAdd(&ssum[fb + 2], o0.z); atomicAdd(&ssum[fb + 3], o0.w);
        atomicAdd(&ssum[fb + 4], o1.x); atomicAdd(&ssum[fb + 5], o1.y);
        atomicAdd(&ssum[fb + 6], o1.z); atomicAdd(&ssum[fb + 7], o1.w);
    }
    __syncthreads();
    if (tid < 32) {
        int bucket = blockIdx.x & 127;  // spread-bucket mean (R2 lesson)
        atomicAdd(&mean_acc[bucket * 32 + tid], ssum[tid]);
    }
}

__global__ void write_mean_kernel(const float* __restrict__ mean_acc,
                                  float* __restrict__ out_tail, float invN) {
    int f = threadIdx.x;
    if (f < 32) {
        float s = 0.0f;
        for (int b = 0; b < 128; ++b) s += mean_acc[b * 32 + f];
        out_tail[f] = s * invN;
    }
}

extern "C" void kernel_launch(void* const* d_in, const int* in_sizes, int n_in,
                              void* d_out, int out_size, void* d_ws,
                              size_t ws_size, hipStream_t stream) {
    const float* x  = (const float*)d_in[0];
    const int*   ei = (const int*)d_in[1];
    const float* ew = (const float*)d_in[2];
    const float* W1 = (const float*)d_in[3];
    const float* b1 = (const float*)d_in[4];
    const float* W2 = (const float*)d_in[5];
    const float* b2 = (const float*)d_in[6];
    const float* W3 = (const float*)d_in[7];
    const float* b3 = (const float*)d_in[8];

    const int N = in_sizes[0] / 128;
    const int E = in_sizes[1] / 2;
    const int* src = ei;
    const int* dst = ei + E;

    const int NB = (N + 255) >> 8;          // 256-node coarse buckets
    const int EPB = (E + G - 1) / G;        // edges per pass-A/B block

    float* out = (float*)d_out;
    char* wsp = (char*)d_ws;
    auto carve = [&](size_t bytes) {
        char* p = wsp;
        wsp += (bytes + 255) & ~(size_t)255;
        return p;
    };
    float*  dinv       = (float*)carve((size_t)N * 4);
    int*    offs       = (int*)carve((size_t)(N + 1) * 4);
    int*    bucketBase = (int*)carve((MAXB + 1) * 4);
    float*  mean       = (float*)carve(128 * 32 * 4);   // 16384 B
    int*    totals     = (int*)carve(MAXB * 4);         // contiguous w/ mean
    int*    histG      = (int*)carve((size_t)MAXB * G * 4);
    int*    blockOffs  = (int*)carve((size_t)MAXB * G * 4);
    int2*   tmp        = (int2*)carve((size_t)E * 8);
    int2*   edges      = (int2*)carve((size_t)E * 8);
    ushort* hA         = (ushort*)carve((size_t)N * 64 * 2);
    ushort* hB         = (ushort*)carve((size_t)N * 64 * 2);
    ushort* W1T        = (ushort*)carve(128 * 64 * 2);
    ushort* W2T        = (ushort*)carve(64 * 64 * 2);
    ushort* W3T        = (ushort*)carve(64 * 32 * 2);

    const int nb_a = (N + 15) / 16;  // agg kernels: 16 nodes per 256-block
    const int nb_g = (N + 63) / 64;  // MFMA gemm: 64 nodes/block

    // one memset covers mean (16384 B) + totals (2048 B), carved contiguous
    hipMemsetAsync(mean, 0, 128 * 32 * 4 + MAXB * 4, stream);

    // ---- CSR build: LDS hist (+W transposes +totals atomics) -> scan ->
    //      block offs -> bucket scatter -> fine counting sort ----
    passA_hist_kernel<<<G, 1024, 0, stream>>>(dst, histG, totals, W1, W2, W3,
                                              W1T, W2T, W3T, E, EPB);
    bucket_scan_kernel<<<1, 512, 0, stream>>>(totals, bucketBase, NB, E);
    block_offs_kernel<<<NB, G, 0, stream>>>(histG, bucketBase, blockOffs);
    passB_scatter_kernel<<<G, 1024, 0, stream>>>(src, dst, ew, blockOffs, tmp,
                                                 E, EPB, NB);
    fine_kernel<<<NB, 512, 0, stream>>>(tmp, bucketBase, offs, edges, dinv, N,
                                        E, NB);

    // ---- layer 1: hA = bf16(dinv * (x @ W1)); hB = dinv*(A_ew hA + hA) ----
    gemm_mfma_kernel<128, 64, false, false, false>
        <<<nb_g, 256, 0, stream>>>(x, W1T, nullptr, dinv, hA, N);
    agg64_kernel<<<nb_a, 256, 0, stream>>>(hA, edges, offs, dinv, hB, N);

    // ---- layer 2 ----
    gemm_mfma_kernel<64, 64, true, true, true>
        <<<nb_g, 256, 0, stream>>>(hB, W2T, b1, dinv, hA, N);
    agg64_kernel<<<nb_a, 256, 0, stream>>>(hA, edges, offs, dinv, hB, N);

    // ---- layer 3: out = dinv*(A_ew hA3 + hA3) + b3; mean pool ----
    gemm_mfma_kernel<64, 32, true, true, true>
        <<<nb_g, 256, 0, stream>>>(hB, W3T, b2, dinv, hA, N);
    agg32_final_kernel<<<nb_a, 256, 0, stream>>>(hA, edges, offs, dinv, b3,
                                                 out, mean, N);

    // ---- epilogue: fold mean buckets ----
    write_mean_kernel<<<1, 32, 0, stream>>>(mean, out + (size_t)N * 32,
                                            1.0f / (float)N);
}